// Round 1
// baseline (1751.571 us; speedup 1.0000x reference)
//
#include <hip/hip_runtime.h>

#define NPTS   120000
#define NOFF   28      // 27 neighbor offsets + 1 point-transform slot
#define CHUNKS 7       // 448 / 64

typedef __bf16 bf16;
typedef __bf16 bf16x8 __attribute__((ext_vector_type(8)));
typedef float  f32x4  __attribute__((ext_vector_type(4)));

// ---------------- weight prep: pack (Wz|Wr) -> WB1 [koff][chunk][kseg][n(256)][8k] bf16
__global__ void wprep1(const float* __restrict__ Wz, const float* __restrict__ Wzp,
                       const float* __restrict__ Wr, const float* __restrict__ Wrp,
                       bf16* __restrict__ WB1)
{
    int bid  = blockIdx.x;          // 28*7*8 = 1568
    int koff = bid / 56;
    int rem  = bid % 56;
    int ch   = rem / 8;
    int kseg = rem % 8;
    int n    = threadIdx.x;         // 256
    int cinb = ch * 64 + kseg * 8;
    bf16x8 v;
    if (n < 128) {
        int col = n;
        #pragma unroll
        for (int j = 0; j < 8; ++j) {
            int cin = cinb + j;
            float w = (koff < 27) ? Wz[((long)koff * 448 + cin) * 128 + col]
                                  : Wzp[(long)cin * 128 + col];
            v[j] = (bf16)w;
        }
    } else {
        int col = n - 128;
        #pragma unroll
        for (int j = 0; j < 8; ++j) {
            int cin = cinb + j;
            float w = (koff < 27) ? Wr[((long)koff * 448 + cin) * 128 + col]
                                  : Wrp[(long)cin * 128 + col];
            v[j] = (bf16)w;
        }
    }
    *(bf16x8*)(WB1 + ((long)bid * 256 + n) * 8) = v;
}

// ---------------- weight prep: pack Wq -> WB2 [koff][chunk][kseg][n(128)][8k] bf16
__global__ void wprep2(const float* __restrict__ Wq, const float* __restrict__ Wqp,
                       bf16* __restrict__ WB2)
{
    int bid  = blockIdx.x;          // 1568
    int koff = bid / 56;
    int rem  = bid % 56;
    int ch   = rem / 8;
    int kseg = rem % 8;
    int n    = threadIdx.x;         // 128
    int cinb = ch * 64 + kseg * 8;
    bf16x8 v;
    #pragma unroll
    for (int j = 0; j < 8; ++j) {
        int cin = cinb + j;
        float w = (koff < 27) ? Wq[((long)koff * 448 + cin) * 128 + n]
                              : Wqp[(long)cin * 128 + n];
        v[j] = (bf16)w;
    }
    *(bf16x8*)(WB2 + ((long)bid * 128 + n) * 8) = v;
}

// ---------------- feature prep: F1 = bf16([h|x]); F2[:,128:448] = bf16(x)
__global__ void fprep(const float* __restrict__ h, const float* __restrict__ x,
                      bf16* __restrict__ F1, bf16* __restrict__ F2)
{
    long i = (long)blockIdx.x * blockDim.x + threadIdx.x;
    if (i >= (long)NPTS * 448) return;
    int p = (int)(i / 448);
    int c = (int)(i % 448);
    float v = (c < 128) ? h[(long)p * 128 + c] : x[(long)p * 320 + (c - 128)];
    F1[i] = (bf16)v;
    if (c >= 128) F2[i] = (bf16)v;
}

// ---------------- gather-GEMM
// GATE==1: NCOLS=256, cols 0..127 -> z=sigmoid -> zbuf (fp32), cols 128..255 -> r=sigmoid,
//          F2[:,c-128] = bf16(r*h).   GATE==2: NCOLS=128, q=tanh, out=(1-z)h+zq.
template<int NCOLS, int GATE>
__global__ __launch_bounds__(NCOLS * 2)
void gconv(const bf16* __restrict__ F, const int* __restrict__ nbr,
           const bf16* __restrict__ WB, const float* __restrict__ b0,
           const float* __restrict__ b1, const float* __restrict__ hbuf,
           float* __restrict__ zbuf, bf16* __restrict__ f2,
           float* __restrict__ out, const bf16* __restrict__ zrow)
{
    constexpr int THREADS = NCOLS * 2;
    constexpr int AP = 1024 / THREADS;          // A-tile 16B units per thread
    constexpr int BP = (NCOLS * 8) / THREADS;   // B-tile 16B units per thread (=4)

    __shared__ __align__(16) bf16 lA[8 * 128 * 8];      // [kseg][row][8]
    __shared__ __align__(16) bf16 lB[8 * NCOLS * 8];    // [kseg][col][8]
    __shared__ int lidx[128];

    const int t    = threadIdx.x;
    const int lane = t & 63;
    const int w    = t >> 6;
    const int m0   = (w & 1) * 64;
    const int n0   = (w >> 1) * 64;
    const int base = blockIdx.x * 128;
    const int ar   = t & 127;        // A row this thread stages
    const int aks0 = t >> 7;

    f32x4 acc[4][4];
    #pragma unroll
    for (int i = 0; i < 4; ++i)
        #pragma unroll
        for (int j = 0; j < 4; ++j)
            acc[i][j] = {0.f, 0.f, 0.f, 0.f};

    const bf16x8* lAv = (const bf16x8*)lA;
    const bf16x8* lBv = (const bf16x8*)lB;

    for (int koff = 0; koff < NOFF; ++koff) {
        __syncthreads();
        if (t < 128) {
            int p = base + t;
            int idx = -1;
            if (p < NPTS) idx = (koff == 27) ? p : nbr[(long)p * 27 + koff];
            lidx[t] = idx;
        }
        __syncthreads();
        const int myidx = lidx[ar];
        const bf16* arow = (myidx >= 0) ? (F + (long)myidx * 448) : zrow;

        for (int ch = 0; ch < CHUNKS; ++ch) {
            // stage A tile (128 rows x 64 k) -- gathered rows, 16B per lane
            #pragma unroll
            for (int p = 0; p < AP; ++p) {
                int kseg = aks0 + p * (THREADS / 128);
                __builtin_amdgcn_global_load_lds(
                    (void*)(arow + ch * 64 + kseg * 8),
                    (void*)(lA + ((long)t + (long)p * THREADS) * 8),
                    16, 0, 0);
            }
            // stage B tile (64 k x NCOLS) -- contiguous packed weights
            const bf16* bsrc = WB + (long)(koff * CHUNKS + ch) * (NCOLS * 64);
            #pragma unroll
            for (int p = 0; p < BP; ++p) {
                __builtin_amdgcn_global_load_lds(
                    (void*)(bsrc + ((long)t + (long)p * THREADS) * 8),
                    (void*)(lB + ((long)t + (long)p * THREADS) * 8),
                    16, 0, 0);
            }
            __syncthreads();
            #pragma unroll
            for (int kk = 0; kk < 2; ++kk) {
                const int aseg = kk * 4 + (lane >> 4);
                bf16x8 af[4], bfr[4];
                #pragma unroll
                for (int mi = 0; mi < 4; ++mi)
                    af[mi] = lAv[aseg * 128 + m0 + mi * 16 + (lane & 15)];
                #pragma unroll
                for (int ni = 0; ni < 4; ++ni)
                    bfr[ni] = lBv[aseg * NCOLS + n0 + ni * 16 + (lane & 15)];
                #pragma unroll
                for (int mi = 0; mi < 4; ++mi)
                    #pragma unroll
                    for (int ni = 0; ni < 4; ++ni)
                        acc[mi][ni] = __builtin_amdgcn_mfma_f32_16x16x32_bf16(
                            af[mi], bfr[ni], acc[mi][ni], 0, 0, 0);
            }
            __syncthreads();
        }
    }

    // epilogue: C/D layout col=lane&15, row=(lane>>4)*4+reg  [m89/m91]
    const int quad = lane >> 4;
    const int lc   = lane & 15;
    #pragma unroll
    for (int mi = 0; mi < 4; ++mi) {
        int rb = m0 + mi * 16 + quad * 4;
        #pragma unroll
        for (int ni = 0; ni < 4; ++ni) {
            int c = n0 + ni * 16 + lc;
            f32x4 v = acc[mi][ni];
            #pragma unroll
            for (int rg = 0; rg < 4; ++rg) {
                int p = base + rb + rg;
                if (p < NPTS) {
                    float pre = v[rg];
                    if constexpr (GATE == 1) {
                        if (c < 128) {
                            float z = 1.f / (1.f + __expf(-(pre + b0[c])));
                            zbuf[(long)p * 128 + c] = z;
                        } else {
                            int cc = c - 128;
                            float r = 1.f / (1.f + __expf(-(pre + b1[cc])));
                            f2[(long)p * 448 + cc] = (bf16)(r * hbuf[(long)p * 128 + cc]);
                        }
                    } else {
                        float q  = tanhf(pre + b0[c]);
                        float z  = zbuf[(long)p * 128 + c];
                        float hv = hbuf[(long)p * 128 + c];
                        out[(long)p * 128 + c] = (1.f - z) * hv + z * q;
                    }
                }
            }
        }
    }
}

extern "C" void kernel_launch(void* const* d_in, const int* in_sizes, int n_in,
                              void* d_out, int out_size, void* d_ws, size_t ws_size,
                              hipStream_t stream)
{
    const float* h   = (const float*)d_in[0];
    const float* x   = (const float*)d_in[1];
    const int*   nbr = (const int*)d_in[2];
    const float* Wz  = (const float*)d_in[3];
    const float* Wzp = (const float*)d_in[4];
    const float* bz  = (const float*)d_in[5];
    const float* Wr  = (const float*)d_in[6];
    const float* Wrp = (const float*)d_in[7];
    const float* br  = (const float*)d_in[8];
    const float* Wq  = (const float*)d_in[9];
    const float* Wqp = (const float*)d_in[10];
    const float* bq  = (const float*)d_in[11];
    float* out = (float*)d_out;

    char* ws = (char*)d_ws;
    bf16* WB1 = (bf16*)ws;  ws += (size_t)1568 * 256 * 8 * 2;   // 6.42 MB
    bf16* WB2 = (bf16*)ws;  ws += (size_t)1568 * 128 * 8 * 2;   // 3.21 MB
    bf16* F1  = (bf16*)ws;  ws += (size_t)NPTS * 448 * 2;       // 107.5 MB
    bf16* F2  = (bf16*)ws;  ws += (size_t)NPTS * 448 * 2;       // 107.5 MB
    bf16* zrow = (bf16*)ws; ws += 1024;                          // zero row for masked gathers
    float* zbuf = out;  // z gate stored in d_out (fp32), overwritten by pass 2

    hipMemsetAsync(zrow, 0, 1024, stream);
    wprep1<<<1568, 256, 0, stream>>>(Wz, Wzp, Wr, Wrp, WB1);
    wprep2<<<1568, 128, 0, stream>>>(Wq, Wqp, WB2);
    long total = (long)NPTS * 448;
    fprep<<<(int)((total + 255) / 256), 256, 0, stream>>>(h, x, F1, F2);

    int grid = (NPTS + 127) / 128;  // 938
    gconv<256, 1><<<grid, 512, 0, stream>>>(F1, nbr, WB1, bz, br, h, zbuf, F2, nullptr, zrow);
    gconv<128, 2><<<grid, 256, 0, stream>>>(F2, nbr, WB2, bq, nullptr, h, zbuf, nullptr, out, zrow);
}

// Round 2
// 1543.299 us; speedup vs baseline: 1.1350x; 1.1350x over previous
//
#include <hip/hip_runtime.h>

#define NPTS   120000
#define NOFF   28      // 27 neighbor offsets + 1 point-transform slot
#define CHUNKS 7       // 448 / 64

typedef __bf16 bf16;
typedef __bf16 bf16x8 __attribute__((ext_vector_type(8)));
typedef float  f32x4  __attribute__((ext_vector_type(4)));

// ---------------- weight prep: pack (Wz|Wr) -> WB1 [koff][chunk][kseg][n(256)][8k] bf16
__global__ void wprep1(const float* __restrict__ Wz, const float* __restrict__ Wzp,
                       const float* __restrict__ Wr, const float* __restrict__ Wrp,
                       bf16* __restrict__ WB1)
{
    int bid  = blockIdx.x;          // 28*7*8 = 1568
    int koff = bid / 56;
    int rem  = bid % 56;
    int ch   = rem / 8;
    int kseg = rem % 8;
    int n    = threadIdx.x;         // 256
    int cinb = ch * 64 + kseg * 8;
    bf16x8 v;
    if (n < 128) {
        int col = n;
        #pragma unroll
        for (int j = 0; j < 8; ++j) {
            int cin = cinb + j;
            float w = (koff < 27) ? Wz[((long)koff * 448 + cin) * 128 + col]
                                  : Wzp[(long)cin * 128 + col];
            v[j] = (bf16)w;
        }
    } else {
        int col = n - 128;
        #pragma unroll
        for (int j = 0; j < 8; ++j) {
            int cin = cinb + j;
            float w = (koff < 27) ? Wr[((long)koff * 448 + cin) * 128 + col]
                                  : Wrp[(long)cin * 128 + col];
            v[j] = (bf16)w;
        }
    }
    *(bf16x8*)(WB1 + ((long)bid * 256 + n) * 8) = v;
}

// ---------------- weight prep: pack Wq -> WB2 [koff][chunk][kseg][n(128)][8k] bf16
__global__ void wprep2(const float* __restrict__ Wq, const float* __restrict__ Wqp,
                       bf16* __restrict__ WB2)
{
    int bid  = blockIdx.x;          // 1568
    int koff = bid / 56;
    int rem  = bid % 56;
    int ch   = rem / 8;
    int kseg = rem % 8;
    int n    = threadIdx.x;         // 128
    int cinb = ch * 64 + kseg * 8;
    bf16x8 v;
    #pragma unroll
    for (int j = 0; j < 8; ++j) {
        int cin = cinb + j;
        float w = (koff < 27) ? Wq[((long)koff * 448 + cin) * 128 + n]
                              : Wqp[(long)cin * 128 + n];
        v[j] = (bf16)w;
    }
    *(bf16x8*)(WB2 + ((long)bid * 128 + n) * 8) = v;
}

// ---------------- feature prep: F1 = bf16([h|x]), vectorized 8 cols/thread
__global__ void fprep(const float* __restrict__ h, const float* __restrict__ x,
                      bf16* __restrict__ F1)
{
    long g = (long)blockIdx.x * blockDim.x + threadIdx.x;
    if (g >= (long)NPTS * 56) return;       // 448/8 = 56 groups per row
    int p = (int)(g / 56);
    int c = (int)(g % 56) * 8;              // 128 divisible by 8 -> no h/x straddle
    const float* src = (c < 128) ? h + (long)p * 128 + c
                                 : x + (long)p * 320 + (c - 128);
    float4 a = ((const float4*)src)[0];
    float4 b = ((const float4*)src)[1];
    bf16x8 v;
    v[0] = (bf16)a.x; v[1] = (bf16)a.y; v[2] = (bf16)a.z; v[3] = (bf16)a.w;
    v[4] = (bf16)b.x; v[5] = (bf16)b.y; v[6] = (bf16)b.z; v[7] = (bf16)b.w;
    *(bf16x8*)(F1 + (long)p * 448 + c) = v;
}

// ---------------- gather-GEMM, MROWS x NCOLS tile, 512 threads (8 waves, 64x64 each)
// GATE==1 (128x256): cols 0..127 -> z=sigmoid -> zbuf(fp32); cols 128..255 -> r=sigmoid,
//                    f2[p*128+cc] = bf16(r*h).
// GATE==2 (256x128): A chunks 0-1 read from f2 (r*h, 128-wide), chunks 2-6 from F (x part);
//                    q=tanh, out=(1-z)h+zq.
template<int MROWS, int NCOLS, int GATE>
__global__ __launch_bounds__(512)
void gconv(const bf16* __restrict__ F, const int* __restrict__ nbr,
           const bf16* __restrict__ WB, const float* __restrict__ b0,
           const float* __restrict__ b1, const float* __restrict__ hbuf,
           float* __restrict__ zbuf, bf16* __restrict__ f2,
           float* __restrict__ out, const bf16* __restrict__ zrow)
{
    constexpr int THREADS = 512;
    constexpr int MW = MROWS / 64;              // m-waves
    constexpr int AP = 8 * MROWS / THREADS;     // A-tile 16B units per thread
    constexpr int BP = 8 * NCOLS / THREADS;     // B-tile 16B units per thread

    __shared__ __align__(16) bf16 lA[8 * MROWS * 8];    // [kseg][row][8]
    __shared__ __align__(16) bf16 lB[8 * NCOLS * 8];    // [kseg][col][8]
    __shared__ int lidx[MROWS];

    const int t    = threadIdx.x;
    const int lane = t & 63;
    const int w    = t >> 6;
    const int m0   = (w % MW) * 64;
    const int n0   = (w / MW) * 64;
    const int base = blockIdx.x * MROWS;
    const int ar   = t % MROWS;          // A row this thread stages
    const int aks0 = t / MROWS;

    f32x4 acc[4][4];
    #pragma unroll
    for (int i = 0; i < 4; ++i)
        #pragma unroll
        for (int j = 0; j < 4; ++j)
            acc[i][j] = {0.f, 0.f, 0.f, 0.f};

    const bf16x8* lAv = (const bf16x8*)lA;
    const bf16x8* lBv = (const bf16x8*)lB;

    for (int koff = 0; koff < NOFF; ++koff) {
        __syncthreads();
        if (t < MROWS) {
            int p = base + t;
            int idx = -1;
            if (p < NPTS) idx = (koff == 27) ? p : nbr[(long)p * 27 + koff];
            lidx[t] = idx;
        }
        __syncthreads();
        const int myidx = lidx[ar];
        const bf16* row1 = (myidx >= 0) ? (F + (long)myidx * 448) : zrow;
        const bf16* row2 = row1;
        if constexpr (GATE == 2)
            row2 = (myidx >= 0) ? (f2 + (long)myidx * 128) : zrow;

        for (int ch = 0; ch < CHUNKS; ++ch) {
            const bf16* asrc = (GATE == 2 && ch < 2) ? (row2 + ch * 64)
                                                     : (row1 + ch * 64);
            // stage A tile (MROWS x 64k) -- gathered rows, 16B per lane
            #pragma unroll
            for (int p = 0; p < AP; ++p) {
                int kseg = aks0 + p * (THREADS / MROWS);
                __builtin_amdgcn_global_load_lds(
                    (void*)(asrc + kseg * 8),
                    (void*)(lA + ((long)t + (long)p * THREADS) * 8),
                    16, 0, 0);
            }
            // stage B tile (64k x NCOLS) -- contiguous packed weights
            const bf16* bsrc = WB + (long)(koff * CHUNKS + ch) * (NCOLS * 64);
            #pragma unroll
            for (int p = 0; p < BP; ++p) {
                __builtin_amdgcn_global_load_lds(
                    (void*)(bsrc + ((long)t + (long)p * THREADS) * 8),
                    (void*)(lB + ((long)t + (long)p * THREADS) * 8),
                    16, 0, 0);
            }
            __syncthreads();
            #pragma unroll
            for (int kk = 0; kk < 2; ++kk) {
                const int aseg = kk * 4 + (lane >> 4);
                bf16x8 af[4], bfr[4];
                #pragma unroll
                for (int mi = 0; mi < 4; ++mi)
                    af[mi] = lAv[aseg * MROWS + m0 + mi * 16 + (lane & 15)];
                #pragma unroll
                for (int ni = 0; ni < 4; ++ni)
                    bfr[ni] = lBv[aseg * NCOLS + n0 + ni * 16 + (lane & 15)];
                #pragma unroll
                for (int mi = 0; mi < 4; ++mi)
                    #pragma unroll
                    for (int ni = 0; ni < 4; ++ni)
                        acc[mi][ni] = __builtin_amdgcn_mfma_f32_16x16x32_bf16(
                            af[mi], bfr[ni], acc[mi][ni], 0, 0, 0);
            }
            __syncthreads();
        }
    }

    // epilogue: C/D layout col=lane&15, row=(lane>>4)*4+reg  [m89/m91]
    const int quad = lane >> 4;
    const int lc   = lane & 15;
    #pragma unroll
    for (int mi = 0; mi < 4; ++mi) {
        int rb = m0 + mi * 16 + quad * 4;
        #pragma unroll
        for (int ni = 0; ni < 4; ++ni) {
            int c = n0 + ni * 16 + lc;
            f32x4 v = acc[mi][ni];
            #pragma unroll
            for (int rg = 0; rg < 4; ++rg) {
                int p = base + rb + rg;
                if (p < NPTS) {
                    float pre = v[rg];
                    if constexpr (GATE == 1) {
                        if (c < 128) {
                            float z = 1.f / (1.f + __expf(-(pre + b0[c])));
                            zbuf[(long)p * 128 + c] = z;
                        } else {
                            int cc = c - 128;
                            float r = 1.f / (1.f + __expf(-(pre + b1[cc])));
                            f2[(long)p * 128 + cc] = (bf16)(r * hbuf[(long)p * 128 + cc]);
                        }
                    } else {
                        float q  = tanhf(pre + b0[c]);
                        float z  = zbuf[(long)p * 128 + c];
                        float hv = hbuf[(long)p * 128 + c];
                        out[(long)p * 128 + c] = (1.f - z) * hv + z * q;
                    }
                }
            }
        }
    }
}

extern "C" void kernel_launch(void* const* d_in, const int* in_sizes, int n_in,
                              void* d_out, int out_size, void* d_ws, size_t ws_size,
                              hipStream_t stream)
{
    const float* h   = (const float*)d_in[0];
    const float* x   = (const float*)d_in[1];
    const int*   nbr = (const int*)d_in[2];
    const float* Wz  = (const float*)d_in[3];
    const float* Wzp = (const float*)d_in[4];
    const float* bz  = (const float*)d_in[5];
    const float* Wr  = (const float*)d_in[6];
    const float* Wrp = (const float*)d_in[7];
    const float* br  = (const float*)d_in[8];
    const float* Wq  = (const float*)d_in[9];
    const float* Wqp = (const float*)d_in[10];
    const float* bq  = (const float*)d_in[11];
    float* out = (float*)d_out;

    char* ws = (char*)d_ws;
    bf16* WB1 = (bf16*)ws;  ws += (size_t)1568 * 256 * 8 * 2;   // 6.42 MB
    bf16* WB2 = (bf16*)ws;  ws += (size_t)1568 * 128 * 8 * 2;   // 3.21 MB
    bf16* F1  = (bf16*)ws;  ws += (size_t)NPTS * 448 * 2;       // 107.5 MB
    bf16* F2  = (bf16*)ws;  ws += (size_t)NPTS * 128 * 2;       // 30.7 MB  (r*h only)
    bf16* zrow = (bf16*)ws; ws += 1024;                          // zero row for masked gathers
    float* zbuf = out;  // z gate stored in d_out (fp32), overwritten by pass 2

    hipMemsetAsync(zrow, 0, 1024, stream);
    wprep1<<<1568, 256, 0, stream>>>(Wz, Wzp, Wr, Wrp, WB1);
    wprep2<<<1568, 128, 0, stream>>>(Wq, Wqp, WB2);
    long groups = (long)NPTS * 56;
    fprep<<<(int)((groups + 255) / 256), 256, 0, stream>>>(h, x, F1);

    gconv<128, 256, 1><<<(NPTS + 127) / 128, 512, 0, stream>>>(
        F1, nbr, WB1, bz, br, h, zbuf, F2, nullptr, zrow);
    gconv<256, 128, 2><<<(NPTS + 255) / 256, 512, 0, stream>>>(
        F1, nbr, WB2, bq, nullptr, h, zbuf, F2, out, zrow);
}